// Round 5
// baseline (574.539 us; speedup 1.0000x reference)
//
#include <hip/hip_runtime.h>
#include <math.h>

// Cross-entropy: loss = mean_b( logsumexp(x[b,:]) - x[b, t_b] )
// B=8192, V=32000 fp32. HBM-bound: ~1.05 GB read once via NT loads.
// Round-5 change: fuse the mean-reduction into the row kernel with the
// last-block pattern (atomic counter + fences), eliminating the second
// kernel's launch/drain gap. Reduction order is fixed -> deterministic.

#define LOG2E 1.4426950408889634f
#define LN2   0.6931471805599453f

typedef float floatx4 __attribute__((ext_vector_type(4)));

__global__ __launch_bounds__(256) void ce_fused_kernel(const float* __restrict__ x,
                                                       const int* __restrict__ tgt,
                                                       float* __restrict__ row_loss,
                                                       unsigned* __restrict__ counter,
                                                       float* __restrict__ out,
                                                       int V, int B) {
    const int row = blockIdx.x;
    const float* __restrict__ xr = x + (size_t)row * (size_t)V;
    const int tid = threadIdx.x;

    const int nvec = V >> 2;                 // 8000 (V % 4 == 0)
    const floatx4* __restrict__ xv = (const floatx4*)xr;

    // Online logsumexp in log2 domain; 4 independent component chains for ILP.
    float m0 = -INFINITY, m1 = -INFINITY, m2 = -INFINITY, m3 = -INFINITY;
    float s0 = 0.f, s1 = 0.f, s2 = 0.f, s3 = 0.f;

    for (int i = tid; i < nvec; i += 256) {
        floatx4 v = __builtin_nontemporal_load(&xv[i]);
        float w0 = v.x * LOG2E, w1 = v.y * LOG2E,
              w2 = v.z * LOG2E, w3 = v.w * LOG2E;
        float n0 = fmaxf(m0, w0);
        s0 = s0 * exp2f(m0 - n0) + exp2f(w0 - n0); m0 = n0;
        float n1 = fmaxf(m1, w1);
        s1 = s1 * exp2f(m1 - n1) + exp2f(w1 - n1); m1 = n1;
        float n2 = fmaxf(m2, w2);
        s2 = s2 * exp2f(m2 - n2) + exp2f(w2 - n2); m2 = n2;
        float n3 = fmaxf(m3, w3);
        s3 = s3 * exp2f(m3 - n3) + exp2f(w3 - n3); m3 = n3;
    }

    // Merge the 4 component chains.
    float M = fmaxf(fmaxf(m0, m1), fmaxf(m2, m3));
    float S = s0 * exp2f(m0 - M) + s1 * exp2f(m1 - M)
            + s2 * exp2f(m2 - M) + s3 * exp2f(m3 - M);

    // Wave (64-lane) butterfly merge.
    #pragma unroll
    for (int off = 1; off < 64; off <<= 1) {
        float om = __shfl_xor(M, off);
        float os = __shfl_xor(S, off);
        float mn = fmaxf(M, om);
        S = S * exp2f(M - mn) + os * exp2f(om - mn);
        M = mn;
    }

    // Cross-wave merge (4 waves).
    __shared__ float sm[4], ss[4];
    __shared__ unsigned is_last;
    const int wave = tid >> 6;
    if ((tid & 63) == 0) { sm[wave] = M; ss[wave] = S; }
    __syncthreads();

    if (tid == 0) {
        float Mf = sm[0], Sf = ss[0];
        #pragma unroll
        for (int w = 1; w < 4; ++w) {
            float om = sm[w], os = ss[w];
            float mn = fmaxf(Mf, om);
            Sf = Sf * exp2f(Mf - mn) + os * exp2f(om - mn);
            Mf = mn;
        }
        float lse = (Mf + log2f(Sf)) * LN2;   // back to natural log
        row_loss[row] = lse - xr[tgt[row]];
        __threadfence();                       // release: row_loss visible device-wide
        unsigned prev = atomicAdd(counter, 1u);
        is_last = (prev == (unsigned)(B - 1)) ? 1u : 0u;
    }
    __syncthreads();

    // Last block to finish performs the deterministic mean (fixed index order).
    if (is_last) {
        __threadfence();                       // acquire: see all row_loss writes
        float acc = 0.0f;
        for (int i = tid; i < B; i += 256) acc += row_loss[i];
        #pragma unroll
        for (int off = 1; off < 64; off <<= 1) acc += __shfl_xor(acc, off);
        __shared__ float sa[4];
        if ((tid & 63) == 0) sa[wave] = acc;
        __syncthreads();
        if (tid == 0) out[0] = (sa[0] + sa[1] + sa[2] + sa[3]) / (float)B;
    }
}

extern "C" void kernel_launch(void* const* d_in, const int* in_sizes, int n_in,
                              void* d_out, int out_size, void* d_ws, size_t ws_size,
                              hipStream_t stream) {
    const float* x = (const float*)d_in[0];
    const int* tgt = (const int*)d_in[1];
    float* out = (float*)d_out;
    float* ws = (float*)d_ws;                  // [0,B): row losses; [B]: counter

    const int B = in_sizes[1];                 // 8192
    const int V = in_sizes[0] / B;             // 32000

    unsigned* counter = (unsigned*)(ws + B);
    hipMemsetAsync(counter, 0, sizeof(unsigned), stream);  // graph-capturable
    ce_fused_kernel<<<B, 256, 0, stream>>>(x, tgt, ws, counter, out, V, B);
}

// Round 6
// 175.871 us; speedup vs baseline: 3.2668x; 3.2668x over previous
//
#include <hip/hip_runtime.h>
#include <math.h>

// Cross-entropy: loss = mean_b( logsumexp(x[b,:]) - x[b, t_b] )
// B=8192, V=32000 fp32. HBM-bound: ~1.05 GB read once via NT loads.
// Round-6: REVERT to the round-4 two-kernel structure (176.2 us best known).
// Fusion via atomic-counter + in-graph memset was 3.3x pathological (the
// 4-byte fill blit alone profiled at ~630 us; per-block __threadfence adds
// device-scope L2 writebacks). Only change vs round 4: hoist the target
// logit gather to the loop head so its latency hides under the stream.

#define LOG2E 1.4426950408889634f
#define LN2   0.6931471805599453f

typedef float floatx4 __attribute__((ext_vector_type(4)));

__global__ __launch_bounds__(256) void ce_row_kernel(const float* __restrict__ x,
                                                     const int* __restrict__ tgt,
                                                     float* __restrict__ row_loss,
                                                     int V) {
    const int row = blockIdx.x;
    const float* __restrict__ xr = x + (size_t)row * (size_t)V;
    const int tid = threadIdx.x;

    // Early, uniform gather of the target logit (broadcast transactions);
    // completes while the stream loop runs. Used only by tid 0 at the end.
    const int t = tgt[row];
    const float tv = xr[t];

    const int nvec = V >> 2;                 // 8000 (V % 4 == 0)
    const floatx4* __restrict__ xv = (const floatx4*)xr;

    // Online logsumexp in log2 domain; 4 independent component chains for ILP.
    float m0 = -INFINITY, m1 = -INFINITY, m2 = -INFINITY, m3 = -INFINITY;
    float s0 = 0.f, s1 = 0.f, s2 = 0.f, s3 = 0.f;

    for (int i = tid; i < nvec; i += 256) {
        floatx4 v = __builtin_nontemporal_load(&xv[i]);
        float w0 = v.x * LOG2E, w1 = v.y * LOG2E,
              w2 = v.z * LOG2E, w3 = v.w * LOG2E;
        float n0 = fmaxf(m0, w0);
        s0 = s0 * exp2f(m0 - n0) + exp2f(w0 - n0); m0 = n0;
        float n1 = fmaxf(m1, w1);
        s1 = s1 * exp2f(m1 - n1) + exp2f(w1 - n1); m1 = n1;
        float n2 = fmaxf(m2, w2);
        s2 = s2 * exp2f(m2 - n2) + exp2f(w2 - n2); m2 = n2;
        float n3 = fmaxf(m3, w3);
        s3 = s3 * exp2f(m3 - n3) + exp2f(w3 - n3); m3 = n3;
    }

    // Merge the 4 component chains.
    float M = fmaxf(fmaxf(m0, m1), fmaxf(m2, m3));
    float S = s0 * exp2f(m0 - M) + s1 * exp2f(m1 - M)
            + s2 * exp2f(m2 - M) + s3 * exp2f(m3 - M);

    // Wave (64-lane) butterfly merge.
    #pragma unroll
    for (int off = 1; off < 64; off <<= 1) {
        float om = __shfl_xor(M, off);
        float os = __shfl_xor(S, off);
        float mn = fmaxf(M, om);
        S = S * exp2f(M - mn) + os * exp2f(om - mn);
        M = mn;
    }

    // Cross-wave merge (4 waves).
    __shared__ float sm[4], ss[4];
    const int wave = tid >> 6;
    if ((tid & 63) == 0) { sm[wave] = M; ss[wave] = S; }
    __syncthreads();

    if (tid == 0) {
        float Mf = sm[0], Sf = ss[0];
        #pragma unroll
        for (int w = 1; w < 4; ++w) {
            float om = sm[w], os = ss[w];
            float mn = fmaxf(Mf, om);
            Sf = Sf * exp2f(Mf - mn) + os * exp2f(om - mn);
            Mf = mn;
        }
        float lse = (Mf + log2f(Sf)) * LN2;   // back to natural log
        row_loss[row] = lse - tv;
    }
}

// Deterministic single-block reduction of per-row losses -> mean.
__global__ __launch_bounds__(256) void ce_reduce_kernel(const float* __restrict__ row_loss,
                                                        float* __restrict__ out, int B) {
    float acc = 0.0f;
    for (int i = threadIdx.x; i < B; i += 256) acc += row_loss[i];
    #pragma unroll
    for (int off = 1; off < 64; off <<= 1) acc += __shfl_xor(acc, off);
    __shared__ float sa[4];
    if ((threadIdx.x & 63) == 0) sa[threadIdx.x >> 6] = acc;
    __syncthreads();
    if (threadIdx.x == 0) out[0] = (sa[0] + sa[1] + sa[2] + sa[3]) / (float)B;
}

extern "C" void kernel_launch(void* const* d_in, const int* in_sizes, int n_in,
                              void* d_out, int out_size, void* d_ws, size_t ws_size,
                              hipStream_t stream) {
    const float* x = (const float*)d_in[0];
    const int* tgt = (const int*)d_in[1];
    float* out = (float*)d_out;
    float* ws = (float*)d_ws;   // B floats of per-row loss

    const int B = in_sizes[1];                 // 8192
    const int V = in_sizes[0] / B;             // 32000

    ce_row_kernel<<<B, 256, 0, stream>>>(x, tgt, ws, V);
    ce_reduce_kernel<<<1, 256, 0, stream>>>(ws, out, B);
}